// Round 6
// baseline (14051.549 us; speedup 1.0000x reference)
//
#include <hip/hip_runtime.h>
#include <hip/hip_bf16.h>

#define BB 32
#define SS 128
#define CC 128
#define HH 128
#define OO 64

typedef float vf4 __attribute__((ext_vector_type(4)));

__device__ __forceinline__ float sigmoidf_(float x) {
    return 1.0f / (1.0f + __expf(-x));
}
__device__ __forceinline__ float tanh_fast_(float x) {
    return 1.0f - 2.0f / (__expf(2.0f * x) + 1.0f);  // |x| small here, no overflow
}

// Quad butterfly add on the VALU pipe. 0xB1 = xor1, 0x4E = xor2 (quad_perm).
template <int CTRL>
__device__ __forceinline__ float dpp_add(float v) {
    int m = __builtin_amdgcn_update_dpp(0, __builtin_bit_cast(int, v),
                                        CTRL, 0xF, 0xF, true);
    return v + __builtin_bit_cast(float, m);
}

// One workgroup per (direction, batch). 1024 threads = 16 waves = 4 waves/SIMD.
// Thread (j = t>>3, oct = t&7) computes gate rows j (r), j+128 (z), j+256 (n)
// over octet `oct` (16 floats) of the 128-wide dot.
// Per-thread weights: 12 vf4 = 48 VGPRs; persistent live set ~60, peak ~105 —
// UNDER the hard 128-VGPR cap that 4 waves/SIMD imposes, so the allocator
// keeps weights architecturally resident (rounds 2-5: 96-float sets got
// AGPR-shuffled with v_accvgpr_read copies every step -> VALU 2x inflation).
// Octet partial sums: dpp xor1 + dpp xor2 (within quad) + __shfl_xor(4).
// h in LDS: octet o's 16-float segment at float-offset o*20 -> the wave's 8
// broadcast b128 addresses land on 8 disjoint 4-bank groups (no conflicts).
__global__ __launch_bounds__(1024) void gru_chain_kernel(
    const float* __restrict__ x,       // (B,S,C)
    const float* __restrict__ h_prev,  // (2,B,H)
    const float* __restrict__ Wih_f, const float* __restrict__ Whh_f,
    const float* __restrict__ bih_f, const float* __restrict__ bhh_f,
    const float* __restrict__ Wih_b, const float* __restrict__ Whh_b,
    const float* __restrict__ bih_b, const float* __restrict__ bhh_b,
    float* __restrict__ hsnap)         // (2, C, B, H) column-end snapshots
{
    const int wg = blockIdx.x;
    const int d  = wg >> 5;        // 0 = forward, 1 = backward
    const int b  = wg & 31;
    const int t  = threadIdx.x;    // 0..1023
    const int j  = t >> 3;         // hidden index 0..127
    const int o  = t & 7;          // octet of the dot (16 floats)

    const float* __restrict__ Wih = d ? Wih_b : Wih_f;
    const float* __restrict__ Whh = d ? Whh_b : Whh_f;
    const float* __restrict__ bih = d ? bih_b : bih_f;
    const float* __restrict__ bhh = d ? bhh_b : bhh_f;

    __shared__ float xs[SS * CC];      // 64KB, x[b] slice (S,C) layout
    __shared__ float hbuf[2][160];     // octet o's segment at float-offset o*20

    // stage x[b] (16384 contiguous floats) into LDS, coalesced float4
    {
        const float4* xb4 = reinterpret_cast<const float4*>(x + (size_t)b * SS * CC);
        float4* xs4 = reinterpret_cast<float4*>(xs);
        #pragma unroll
        for (int i = 0; i < 4; ++i) xs4[t + i * 1024] = xb4[t + i * 1024];
    }

    // 12 NAMED vf4 weight registers (48 VGPRs): rows j, j+128, j+256, octet o
    const vf4* pr = reinterpret_cast<const vf4*>(Whh + (j          ) * HH + o * 16);
    const vf4* pz = reinterpret_cast<const vf4*>(Whh + (j +     HH ) * HH + o * 16);
    const vf4* pn = reinterpret_cast<const vf4*>(Whh + (j + 2 * HH ) * HH + o * 16);
    vf4 wr0 = pr[0], wr1 = pr[1], wr2 = pr[2], wr3 = pr[3];
    vf4 wz0 = pz[0], wz1 = pz[1], wz2 = pz[2], wz3 = pz[3];
    vf4 wn0 = pn[0], wn1 = pn[1], wn2 = pn[2], wn3 = pn[3];

    const float wih_r = Wih[j];
    const float wih_z = Wih[j + HH];
    const float wih_n = Wih[j + 2 * HH];
    const float brz_r = bih[j]      + bhh[j];        // folded r bias
    const float brz_z = bih[j + HH] + bhh[j + HH];   // folded z bias
    const float bih_n = bih[j + 2 * HH];
    const float bhh_n = bhh[j + 2 * HH];

    float hp = h_prev[(d * BB + b) * HH + j];        // own h (all 8 lanes)
    const int hrd = o * 20;                          // read base (floats)
    const int hwr = ((j >> 4) * 20) + (j & 15);      // write slot for h[j]
    if (o == 0) hbuf[0][hwr] = hp;
    __syncthreads();

    // One GRU step: read h from hbuf[SRC], write new h to hbuf[DST].
#define GSTEP(SRC, DST, TSS)                                                  \
    {                                                                         \
        const int tt = d ? (SS - 1 - (TSS)) : (TSS);                          \
        const float xv = xs[tt * CC + c];       /* uniform broadcast read */  \
        const vf4* h4 = reinterpret_cast<const vf4*>(&hbuf[SRC][hrd]);        \
        vf4 hv = h4[0];                                                       \
        vf4 ar = wr0 * hv, az = wz0 * hv, an = wn0 * hv;                      \
        hv = h4[1];                                                           \
        ar = __builtin_elementwise_fma(wr1, hv, ar);                          \
        az = __builtin_elementwise_fma(wz1, hv, az);                          \
        an = __builtin_elementwise_fma(wn1, hv, an);                          \
        hv = h4[2];                                                           \
        ar = __builtin_elementwise_fma(wr2, hv, ar);                          \
        az = __builtin_elementwise_fma(wz2, hv, az);                          \
        an = __builtin_elementwise_fma(wn2, hv, an);                          \
        hv = h4[3];                                                           \
        ar = __builtin_elementwise_fma(wr3, hv, ar);                          \
        az = __builtin_elementwise_fma(wz3, hv, az);                          \
        an = __builtin_elementwise_fma(wn3, hv, an);                          \
        float sr = (ar.x + ar.y) + (ar.z + ar.w);                             \
        float sz = (az.x + az.y) + (az.z + az.w);                             \
        float sn = (an.x + an.y) + (an.z + an.w);                             \
        sr += __shfl_xor(sr, 4);                /* cross-quad first */        \
        sz += __shfl_xor(sz, 4);                                              \
        sn += __shfl_xor(sn, 4);                                              \
        sr = dpp_add<0xB1>(sr); sr = dpp_add<0x4E>(sr);                       \
        sz = dpp_add<0xB1>(sz); sz = dpp_add<0x4E>(sz);                       \
        sn = dpp_add<0xB1>(sn); sn = dpp_add<0x4E>(sn);                       \
        const float r = sigmoidf_(fmaf(xv, wih_r, sr + brz_r));               \
        const float z = sigmoidf_(fmaf(xv, wih_z, sz + brz_z));               \
        const float gi_n = fmaf(xv, wih_n, bih_n);                            \
        const float n = tanh_fast_(fmaf(r, sn + bhh_n, gi_n));                \
        hp = fmaf(z, hp - n, n);                /* (1-z)*n + z*h */           \
        if (o == 0) hbuf[DST][hwr] = hp;                                      \
        __syncthreads();                                                      \
    }

    for (int c = 0; c < CC; ++c) {
        for (int ts = 0; ts < SS; ts += 2) {
            GSTEP(0, 1, ts)        // h: buf0 -> buf1
            GSTEP(1, 0, ts + 1)    // h: buf1 -> buf0
        }
        if (o == 0) {
            hsnap[(((size_t)d * CC + c) * BB + b) * HH + j] = hp;
        }
    }
#undef GSTEP
}

// One block (= one wave of 64 threads) per (c,b): FC + ReLU + softmax over O=64.
__global__ __launch_bounds__(64) void fc_softmax_kernel(
    const float* __restrict__ hsnap,   // (2, C, B, H)
    const float* __restrict__ W_fc,    // (O, 2H)
    const float* __restrict__ b_fc,    // (O,)
    float* __restrict__ out)           // (B, C, O)
{
    const int cb = blockIdx.x;         // c * B + b
    const int c  = cb >> 5;
    const int b  = cb & 31;
    const int o  = threadIdx.x;        // 0..63

    __shared__ float feat[2 * HH];     // [hf, hb]
    #pragma unroll
    for (int i = 0; i < 4; ++i) {
        const int idx = i * 64 + o;            // 0..255
        const int dd  = idx >> 7;              // 0: hf, 1: hb
        const int jj  = idx & (HH - 1);
        feat[idx] = hsnap[(((size_t)dd * CC + c) * BB + b) * HH + jj];
    }
    __syncthreads();

    float acc = 0.f;
    const float4* wrow = reinterpret_cast<const float4*>(W_fc + o * 2 * HH);
    const float4* f4   = reinterpret_cast<const float4*>(feat);
    #pragma unroll
    for (int k = 0; k < 64; ++k) {
        const float4 wv = wrow[k];
        const float4 fv = f4[k];
        acc = fmaf(wv.x, fv.x, acc);
        acc = fmaf(wv.y, fv.y, acc);
        acc = fmaf(wv.z, fv.z, acc);
        acc = fmaf(wv.w, fv.w, acc);
    }
    float v = fmaxf(acc + b_fc[o], 0.0f);

    float m = v;
    #pragma unroll
    for (int off = 32; off; off >>= 1) m = fmaxf(m, __shfl_xor(m, off));
    const float e = __expf(v - m);
    float ssum = e;
    #pragma unroll
    for (int off = 32; off; off >>= 1) ssum += __shfl_xor(ssum, off);

    out[((size_t)b * CC + c) * OO + o] = e / ssum;
}

extern "C" void kernel_launch(void* const* d_in, const int* in_sizes, int n_in,
                              void* d_out, int out_size, void* d_ws, size_t ws_size,
                              hipStream_t stream) {
    const float* x      = (const float*)d_in[0];
    const float* h_prev = (const float*)d_in[1];
    const float* Wih_f  = (const float*)d_in[2];
    const float* Whh_f  = (const float*)d_in[3];
    const float* bih_f  = (const float*)d_in[4];
    const float* bhh_f  = (const float*)d_in[5];
    const float* Wih_b  = (const float*)d_in[6];
    const float* Whh_b  = (const float*)d_in[7];
    const float* bih_b  = (const float*)d_in[8];
    const float* bhh_b  = (const float*)d_in[9];
    const float* W_fc   = (const float*)d_in[10];
    const float* b_fc   = (const float*)d_in[11];
    float* out   = (float*)d_out;
    float* hsnap = (float*)d_ws;   // 2*C*B*H*4 = 4 MiB of scratch

    gru_chain_kernel<<<64, 1024, 0, stream>>>(x, h_prev, Wih_f, Whh_f, bih_f, bhh_f,
                                              Wih_b, Whh_b, bih_b, bhh_b, hsnap);
    fc_softmax_kernel<<<CC * BB, 64, 0, stream>>>(hsnap, W_fc, b_fc, out);
}

// Round 7
// 8797.647 us; speedup vs baseline: 1.5972x; 1.5972x over previous
//
#include <hip/hip_runtime.h>
#include <hip/hip_bf16.h>

#define BB 32
#define SS 128
#define CC 128
#define HH 128
#define OO 64

typedef float vf4 __attribute__((ext_vector_type(4)));
typedef _Float16 f16;
typedef f16 h2 __attribute__((ext_vector_type(2)));
typedef f16 h8 __attribute__((ext_vector_type(8)));   // 16B = 4 VGPRs

__device__ __forceinline__ float sigmoidf_(float x) {
    return 1.0f / (1.0f + __expf(-x));
}
__device__ __forceinline__ float tanh_fast_(float x) {
    return 1.0f - 2.0f / (__expf(2.0f * x) + 1.0f);  // |x| small here, no overflow
}

// Quad butterfly add on the VALU pipe. 0xB1 = xor1, 0x4E = xor2 (quad_perm).
template <int CTRL>
__device__ __forceinline__ float dpp_add(float v) {
    int m = __builtin_amdgcn_update_dpp(0, __builtin_bit_cast(int, v),
                                        CTRL, 0xF, 0xF, true);
    return v + __builtin_bit_cast(float, m);
}

// 8-element f16 dot with f32 accumulate: 4x v_dot2_f32_f16.
__device__ __forceinline__ float dot8(h8 w, h8 h, float acc) {
    acc = __builtin_amdgcn_fdot2(__builtin_shufflevector(w, w, 0, 1),
                                 __builtin_shufflevector(h, h, 0, 1), acc, false);
    acc = __builtin_amdgcn_fdot2(__builtin_shufflevector(w, w, 2, 3),
                                 __builtin_shufflevector(h, h, 2, 3), acc, false);
    acc = __builtin_amdgcn_fdot2(__builtin_shufflevector(w, w, 4, 5),
                                 __builtin_shufflevector(h, h, 4, 5), acc, false);
    acc = __builtin_amdgcn_fdot2(__builtin_shufflevector(w, w, 6, 7),
                                 __builtin_shufflevector(h, h, 6, 7), acc, false);
    return acc;
}

__device__ __forceinline__ h8 cvt8(const float* p) {
    h8 r;
    #pragma unroll
    for (int i = 0; i < 8; ++i) r[i] = (f16)p[i];
    return r;
}

// One workgroup per (direction, batch). 512 threads = 8 waves, 2 waves/SIMD.
// Thread (j = t>>2, q = t&3) computes gate rows j (r), j+128 (z), j+256 (n)
// over quarter q (32 of 128 dot elems). f16 weights+h, f32 accumulate via
// v_dot2_f32_f16 -> per-thread weights = 48 VGPRs (12 x h8); total live ~100,
// UNDER the ~128-VGPR cap the scheduler has enforced all session, so the
// weights are finally architecturally resident (R1-R6: every config spilled).
// The f32 carry hp stays in registers -> f16 noise enters only via dot inputs.
// h in LDS as f16, quarter q at half-offset q*40 (80B): the 4 broadcast
// addresses of each ds_read_b128 land on disjoint bank quads (0/20/8/28...).
// Quad partial sums: 2 DPP quad_perm adds (VALU pipe). 1 barrier per step.
__global__ __launch_bounds__(512) void gru_chain_kernel(
    const float* __restrict__ x,       // (B,S,C)
    const float* __restrict__ h_prev,  // (2,B,H)
    const float* __restrict__ Wih_f, const float* __restrict__ Whh_f,
    const float* __restrict__ bih_f, const float* __restrict__ bhh_f,
    const float* __restrict__ Wih_b, const float* __restrict__ Whh_b,
    const float* __restrict__ bih_b, const float* __restrict__ bhh_b,
    float* __restrict__ hsnap)         // (2, C, B, H) column-end snapshots
{
    const int wg = blockIdx.x;
    const int d  = wg >> 5;        // 0 = forward, 1 = backward
    const int b  = wg & 31;
    const int t  = threadIdx.x;    // 0..511
    const int j  = t >> 2;         // hidden index 0..127
    const int q  = t & 3;          // quarter of the dot

    const float* __restrict__ Wih = d ? Wih_b : Wih_f;
    const float* __restrict__ Whh = d ? Whh_b : Whh_f;
    const float* __restrict__ bih = d ? bih_b : bih_f;
    const float* __restrict__ bhh = d ? bhh_b : bhh_f;

    __shared__ float xs[SS * CC];                    // 64KB, x[b] slice
    __shared__ __align__(16) f16 hbuf[2][160];       // quarter q at half-offset q*40

    // stage x[b] (16384 contiguous floats) into LDS, coalesced float4
    {
        const float4* xb4 = reinterpret_cast<const float4*>(x + (size_t)b * SS * CC);
        float4* xs4 = reinterpret_cast<float4*>(xs);
        #pragma unroll
        for (int i = 0; i < 8; ++i) xs4[t + i * 512] = xb4[t + i * 512];
    }

    // 12 NAMED h8 weight registers (48 VGPRs): rows j, j+128, j+256, quarter q
    const float* rowr = Whh + (j          ) * HH + q * 32;
    const float* rowz = Whh + (j +     HH ) * HH + q * 32;
    const float* rown = Whh + (j + 2 * HH ) * HH + q * 32;
    h8 wrA = cvt8(rowr +  0), wrB = cvt8(rowr +  8),
       wrC = cvt8(rowr + 16), wrD = cvt8(rowr + 24);
    h8 wzA = cvt8(rowz +  0), wzB = cvt8(rowz +  8),
       wzC = cvt8(rowz + 16), wzD = cvt8(rowz + 24);
    h8 wnA = cvt8(rown +  0), wnB = cvt8(rown +  8),
       wnC = cvt8(rown + 16), wnD = cvt8(rown + 24);

    const float wih_r = Wih[j];
    const float wih_z = Wih[j + HH];
    const float wih_n = Wih[j + 2 * HH];
    const float brz_r = bih[j]      + bhh[j];        // folded r bias
    const float brz_z = bih[j + HH] + bhh[j + HH];   // folded z bias
    const float bih_n = bih[j + 2 * HH];
    const float bhh_n = bhh[j + 2 * HH];

    float hp = h_prev[(d * BB + b) * HH + j];        // f32 carry (all 4 lanes)
    const int hwr = ((j >> 5) * 40) + (j & 31);      // skewed write slot (halves)
    if (q == 0) hbuf[0][hwr] = (f16)hp;
    __syncthreads();

    // One GRU step: read h (f16) from hbuf[SRC], write new h to hbuf[DST].
#define GSTEP(SRC, DST, TSS)                                                  \
    {                                                                         \
        const int tt = d ? (SS - 1 - (TSS)) : (TSS);                          \
        const float xv = xs[tt * CC + c];       /* uniform broadcast read */  \
        const h8* hb = reinterpret_cast<const h8*>(&hbuf[SRC][q * 40]);       \
        const h8 hv0 = hb[0], hv1 = hb[1], hv2 = hb[2], hv3 = hb[3];          \
        float ra = dot8(wrA, hv0, 0.0f), rb = dot8(wrC, hv2, 0.0f);           \
        float za = dot8(wzA, hv0, 0.0f), zb = dot8(wzC, hv2, 0.0f);           \
        float na = dot8(wnA, hv0, 0.0f), nb = dot8(wnC, hv2, 0.0f);           \
        ra = dot8(wrB, hv1, ra);  rb = dot8(wrD, hv3, rb);                    \
        za = dot8(wzB, hv1, za);  zb = dot8(wzD, hv3, zb);                    \
        na = dot8(wnB, hv1, na);  nb = dot8(wnD, hv3, nb);                    \
        float sr = ra + rb, sz = za + zb, sn = na + nb;                       \
        sr = dpp_add<0xB1>(sr); sr = dpp_add<0x4E>(sr);                       \
        sz = dpp_add<0xB1>(sz); sz = dpp_add<0x4E>(sz);                       \
        sn = dpp_add<0xB1>(sn); sn = dpp_add<0x4E>(sn);                       \
        const float r = sigmoidf_(fmaf(xv, wih_r, sr + brz_r));               \
        const float z = sigmoidf_(fmaf(xv, wih_z, sz + brz_z));               \
        const float gi_n = fmaf(xv, wih_n, bih_n);                            \
        const float n = tanh_fast_(fmaf(r, sn + bhh_n, gi_n));                \
        hp = fmaf(z, hp - n, n);                /* (1-z)*n + z*h  (f32) */    \
        if (q == 0) hbuf[DST][hwr] = (f16)hp;                                 \
        __syncthreads();                                                      \
    }

    for (int c = 0; c < CC; ++c) {
        for (int ts = 0; ts < SS; ts += 2) {
            GSTEP(0, 1, ts)        // h: buf0 -> buf1
            GSTEP(1, 0, ts + 1)    // h: buf1 -> buf0
        }
        if (q == 0) {
            hsnap[(((size_t)d * CC + c) * BB + b) * HH + j] = hp;
        }
    }
#undef GSTEP
}

// One block (= one wave of 64 threads) per (c,b): FC + ReLU + softmax over O=64.
__global__ __launch_bounds__(64) void fc_softmax_kernel(
    const float* __restrict__ hsnap,   // (2, C, B, H)
    const float* __restrict__ W_fc,    // (O, 2H)
    const float* __restrict__ b_fc,    // (O,)
    float* __restrict__ out)           // (B, C, O)
{
    const int cb = blockIdx.x;         // c * B + b
    const int c  = cb >> 5;
    const int b  = cb & 31;
    const int o  = threadIdx.x;        // 0..63

    __shared__ float feat[2 * HH];     // [hf, hb]
    #pragma unroll
    for (int i = 0; i < 4; ++i) {
        const int idx = i * 64 + o;            // 0..255
        const int dd  = idx >> 7;              // 0: hf, 1: hb
        const int jj  = idx & (HH - 1);
        feat[idx] = hsnap[(((size_t)dd * CC + c) * BB + b) * HH + jj];
    }
    __syncthreads();

    float acc = 0.f;
    const float4* wrow = reinterpret_cast<const float4*>(W_fc + o * 2 * HH);
    const float4* f4   = reinterpret_cast<const float4*>(feat);
    #pragma unroll
    for (int k = 0; k < 64; ++k) {
        const float4 wv = wrow[k];
        const float4 fv = f4[k];
        acc = fmaf(wv.x, fv.x, acc);
        acc = fmaf(wv.y, fv.y, acc);
        acc = fmaf(wv.z, fv.z, acc);
        acc = fmaf(wv.w, fv.w, acc);
    }
    float v = fmaxf(acc + b_fc[o], 0.0f);

    float m = v;
    #pragma unroll
    for (int off = 32; off; off >>= 1) m = fmaxf(m, __shfl_xor(m, off));
    const float e = __expf(v - m);
    float ssum = e;
    #pragma unroll
    for (int off = 32; off; off >>= 1) ssum += __shfl_xor(ssum, off);

    out[((size_t)b * CC + c) * OO + o] = e / ssum;
}

extern "C" void kernel_launch(void* const* d_in, const int* in_sizes, int n_in,
                              void* d_out, int out_size, void* d_ws, size_t ws_size,
                              hipStream_t stream) {
    const float* x      = (const float*)d_in[0];
    const float* h_prev = (const float*)d_in[1];
    const float* Wih_f  = (const float*)d_in[2];
    const float* Whh_f  = (const float*)d_in[3];
    const float* bih_f  = (const float*)d_in[4];
    const float* bhh_f  = (const float*)d_in[5];
    const float* Wih_b  = (const float*)d_in[6];
    const float* Whh_b  = (const float*)d_in[7];
    const float* bih_b  = (const float*)d_in[8];
    const float* bhh_b  = (const float*)d_in[9];
    const float* W_fc   = (const float*)d_in[10];
    const float* b_fc   = (const float*)d_in[11];
    float* out   = (float*)d_out;
    float* hsnap = (float*)d_ws;   // 2*C*B*H*4 = 4 MiB of scratch

    gru_chain_kernel<<<64, 512, 0, stream>>>(x, h_prev, Wih_f, Whh_f, bih_f, bhh_f,
                                             Wih_b, Whh_b, bih_b, bhh_b, hsnap);
    fc_softmax_kernel<<<CC * BB, 64, 0, stream>>>(hsnap, W_fc, b_fc, out);
}

// Round 8
// 8739.379 us; speedup vs baseline: 1.6078x; 1.0067x over previous
//
#include <hip/hip_runtime.h>
#include <hip/hip_bf16.h>

#define BB 32
#define SS 128
#define CC 128
#define HH 128
#define OO 64

typedef float vf4 __attribute__((ext_vector_type(4)));
typedef _Float16 f16;
typedef f16 h2 __attribute__((ext_vector_type(2)));
typedef f16 h8 __attribute__((ext_vector_type(8)));   // 16B = 4 VGPRs

__device__ __forceinline__ float sigmoidf_(float x) {
    return 1.0f / (1.0f + __expf(-x));
}
__device__ __forceinline__ float tanh_fast_(float x) {
    return 1.0f - 2.0f / (__expf(2.0f * x) + 1.0f);  // |x| small here, no overflow
}

// Quad butterfly add on the VALU pipe. 0xB1 = xor1, 0x4E = xor2 (quad_perm).
template <int CTRL>
__device__ __forceinline__ float dpp_add(float v) {
    int m = __builtin_amdgcn_update_dpp(0, __builtin_bit_cast(int, v),
                                        CTRL, 0xF, 0xF, true);
    return v + __builtin_bit_cast(float, m);
}

// 8-element f16 dot with f32 accumulate: 4x v_dot2_f32_f16.
__device__ __forceinline__ float dot8(h8 w, h8 h, float acc) {
    acc = __builtin_amdgcn_fdot2(__builtin_shufflevector(w, w, 0, 1),
                                 __builtin_shufflevector(h, h, 0, 1), acc, false);
    acc = __builtin_amdgcn_fdot2(__builtin_shufflevector(w, w, 2, 3),
                                 __builtin_shufflevector(h, h, 2, 3), acc, false);
    acc = __builtin_amdgcn_fdot2(__builtin_shufflevector(w, w, 4, 5),
                                 __builtin_shufflevector(h, h, 4, 5), acc, false);
    acc = __builtin_amdgcn_fdot2(__builtin_shufflevector(w, w, 6, 7),
                                 __builtin_shufflevector(h, h, 6, 7), acc, false);
    return acc;
}

__device__ __forceinline__ h8 cvt8(const float* p) {
    h8 r;
    #pragma unroll
    for (int i = 0; i < 8; ++i) r[i] = (f16)p[i];
    return r;
}

// One workgroup per (direction, batch). 512 threads = 8 waves.
// Thread (j = t>>2, q = t&3): gate rows j (r), j+128 (z), j+256 (n), quarter q
// of the 128-wide dot. f16 weights+h, f32 accumulate via v_dot2_f32_f16.
//
// THE ROUND-8 FIX (R1-R7 all lost the weight-residency fight):
//  (a) LDS padded past 80KB -> only 1 block/CU fits -> 8 waves/CU -> 2
//      waves/SIMD -> the backend's VGPR budget becomes 256 (was 128 from the
//      LDS-derived 2-block occupancy target). Grid = 64 blocks on 256 CUs, so
//      1 block/CU costs nothing.
//  (b) asm "+v" pin on the 12 h8 weight regs: opaque values cannot be
//      REMATERIALIZED (R7 disease: 48 weight re-loads + 96 v_cvt_f16_f32 per
//      step, ~3x VALU inflation), and under a 256 budget there is no spill
//      pressure (R3's pin failed at 192 floats > every budget).
// h in LDS as f16, quarter q at half-offset q*40 (80B): the 4 b128 broadcast
// addresses land on disjoint bank quads. 1 barrier per step.
__global__
__attribute__((amdgpu_flat_work_group_size(512, 512), amdgpu_waves_per_eu(2, 2)))
void gru_chain_kernel(
    const float* __restrict__ x,       // (B,S,C)
    const float* __restrict__ h_prev,  // (2,B,H)
    const float* __restrict__ Wih_f, const float* __restrict__ Whh_f,
    const float* __restrict__ bih_f, const float* __restrict__ bhh_f,
    const float* __restrict__ Wih_b, const float* __restrict__ Whh_b,
    const float* __restrict__ bih_b, const float* __restrict__ bhh_b,
    float* __restrict__ hsnap)         // (2, C, B, H) column-end snapshots
{
    const int wg = blockIdx.x;
    const int d  = wg >> 5;        // 0 = forward, 1 = backward
    const int b  = wg & 31;
    const int t  = threadIdx.x;    // 0..511
    const int j  = t >> 2;         // hidden index 0..127
    const int q  = t & 3;          // quarter of the dot

    const float* __restrict__ Wih = d ? Wih_b : Wih_f;
    const float* __restrict__ Whh = d ? Whh_b : Whh_f;
    const float* __restrict__ bih = d ? bih_b : bih_f;
    const float* __restrict__ bhh = d ? bhh_b : bhh_f;

    // xs padded: total LDS = (16384+4608)*4 + 2*160*2 = 84608 B > 81920 B
    // -> 1 block/CU -> 2 waves/SIMD -> 256-VGPR allocator budget.
    __shared__ float xs[SS * CC + 4608];
    __shared__ __align__(16) f16 hbuf[2][160];       // quarter q at half-offset q*40

    // stage x[b] (16384 contiguous floats) into LDS, coalesced float4
    {
        const float4* xb4 = reinterpret_cast<const float4*>(x + (size_t)b * SS * CC);
        float4* xs4 = reinterpret_cast<float4*>(xs);
        #pragma unroll
        for (int i = 0; i < 8; ++i) xs4[t + i * 512] = xb4[t + i * 512];
    }

    // 12 NAMED h8 weight registers (48 VGPRs): rows j, j+128, j+256, quarter q
    const float* rowr = Whh + (j          ) * HH + q * 32;
    const float* rowz = Whh + (j +     HH ) * HH + q * 32;
    const float* rown = Whh + (j + 2 * HH ) * HH + q * 32;
    h8 wrA = cvt8(rowr +  0), wrB = cvt8(rowr +  8),
       wrC = cvt8(rowr + 16), wrD = cvt8(rowr + 24);
    h8 wzA = cvt8(rowz +  0), wzB = cvt8(rowz +  8),
       wzC = cvt8(rowz + 16), wzD = cvt8(rowz + 24);
    h8 wnA = cvt8(rown +  0), wnB = cvt8(rown +  8),
       wnC = cvt8(rown + 16), wnD = cvt8(rown + 24);
    // pin: opaque to the rematerializer; 256-reg budget -> no spill pressure
    asm volatile("" : "+v"(wrA), "+v"(wrB), "+v"(wrC), "+v"(wrD),
                      "+v"(wzA), "+v"(wzB), "+v"(wzC), "+v"(wzD),
                      "+v"(wnA), "+v"(wnB), "+v"(wnC), "+v"(wnD));

    const float wih_r = Wih[j];
    const float wih_z = Wih[j + HH];
    const float wih_n = Wih[j + 2 * HH];
    const float brz_r = bih[j]      + bhh[j];        // folded r bias
    const float brz_z = bih[j + HH] + bhh[j + HH];   // folded z bias
    const float bih_n = bih[j + 2 * HH];
    const float bhh_n = bhh[j + 2 * HH];

    float hp = h_prev[(d * BB + b) * HH + j];        // f32 carry (all 4 lanes)
    const int hwr = ((j >> 5) * 40) + (j & 31);      // skewed write slot (halves)
    if (q == 0) hbuf[0][hwr] = (f16)hp;
    __syncthreads();

    // One GRU step: read h (f16) from hbuf[SRC], write new h to hbuf[DST].
#define GSTEP(SRC, DST, TSS)                                                  \
    {                                                                         \
        const int tt = d ? (SS - 1 - (TSS)) : (TSS);                          \
        const float xv = xs[tt * CC + c];       /* uniform broadcast read */  \
        const h8* hb = reinterpret_cast<const h8*>(&hbuf[SRC][q * 40]);       \
        const h8 hv0 = hb[0], hv1 = hb[1], hv2 = hb[2], hv3 = hb[3];          \
        float ra = dot8(wrA, hv0, 0.0f), rb = dot8(wrC, hv2, 0.0f);           \
        float za = dot8(wzA, hv0, 0.0f), zb = dot8(wzC, hv2, 0.0f);           \
        float na = dot8(wnA, hv0, 0.0f), nb = dot8(wnC, hv2, 0.0f);           \
        ra = dot8(wrB, hv1, ra);  rb = dot8(wrD, hv3, rb);                    \
        za = dot8(wzB, hv1, za);  zb = dot8(wzD, hv3, zb);                    \
        na = dot8(wnB, hv1, na);  nb = dot8(wnD, hv3, nb);                    \
        float sr = ra + rb, sz = za + zb, sn = na + nb;                       \
        sr = dpp_add<0xB1>(sr); sr = dpp_add<0x4E>(sr);                       \
        sz = dpp_add<0xB1>(sz); sz = dpp_add<0x4E>(sz);                       \
        sn = dpp_add<0xB1>(sn); sn = dpp_add<0x4E>(sn);                       \
        const float r = sigmoidf_(fmaf(xv, wih_r, sr + brz_r));               \
        const float z = sigmoidf_(fmaf(xv, wih_z, sz + brz_z));               \
        const float gi_n = fmaf(xv, wih_n, bih_n);                            \
        const float n = tanh_fast_(fmaf(r, sn + bhh_n, gi_n));                \
        hp = fmaf(z, hp - n, n);                /* (1-z)*n + z*h  (f32) */    \
        if (q == 0) hbuf[DST][hwr] = (f16)hp;                                 \
        __syncthreads();                                                      \
    }

    for (int c = 0; c < CC; ++c) {
        for (int ts = 0; ts < SS; ts += 2) {
            GSTEP(0, 1, ts)        // h: buf0 -> buf1
            GSTEP(1, 0, ts + 1)    // h: buf1 -> buf0
        }
        if (q == 0) {
            hsnap[(((size_t)d * CC + c) * BB + b) * HH + j] = hp;
        }
    }
#undef GSTEP
}

// One block (= one wave of 64 threads) per (c,b): FC + ReLU + softmax over O=64.
__global__ __launch_bounds__(64) void fc_softmax_kernel(
    const float* __restrict__ hsnap,   // (2, C, B, H)
    const float* __restrict__ W_fc,    // (O, 2H)
    const float* __restrict__ b_fc,    // (O,)
    float* __restrict__ out)           // (B, C, O)
{
    const int cb = blockIdx.x;         // c * B + b
    const int c  = cb >> 5;
    const int b  = cb & 31;
    const int o  = threadIdx.x;        // 0..63

    __shared__ float feat[2 * HH];     // [hf, hb]
    #pragma unroll
    for (int i = 0; i < 4; ++i) {
        const int idx = i * 64 + o;            // 0..255
        const int dd  = idx >> 7;              // 0: hf, 1: hb
        const int jj  = idx & (HH - 1);
        feat[idx] = hsnap[(((size_t)dd * CC + c) * BB + b) * HH + jj];
    }
    __syncthreads();

    float acc = 0.f;
    const float4* wrow = reinterpret_cast<const float4*>(W_fc + o * 2 * HH);
    const float4* f4   = reinterpret_cast<const float4*>(feat);
    #pragma unroll
    for (int k = 0; k < 64; ++k) {
        const float4 wv = wrow[k];
        const float4 fv = f4[k];
        acc = fmaf(wv.x, fv.x, acc);
        acc = fmaf(wv.y, fv.y, acc);
        acc = fmaf(wv.z, fv.z, acc);
        acc = fmaf(wv.w, fv.w, acc);
    }
    float v = fmaxf(acc + b_fc[o], 0.0f);

    float m = v;
    #pragma unroll
    for (int off = 32; off; off >>= 1) m = fmaxf(m, __shfl_xor(m, off));
    const float e = __expf(v - m);
    float ssum = e;
    #pragma unroll
    for (int off = 32; off; off >>= 1) ssum += __shfl_xor(ssum, off);

    out[((size_t)b * CC + c) * OO + o] = e / ssum;
}

extern "C" void kernel_launch(void* const* d_in, const int* in_sizes, int n_in,
                              void* d_out, int out_size, void* d_ws, size_t ws_size,
                              hipStream_t stream) {
    const float* x      = (const float*)d_in[0];
    const float* h_prev = (const float*)d_in[1];
    const float* Wih_f  = (const float*)d_in[2];
    const float* Whh_f  = (const float*)d_in[3];
    const float* bih_f  = (const float*)d_in[4];
    const float* bhh_f  = (const float*)d_in[5];
    const float* Wih_b  = (const float*)d_in[6];
    const float* Whh_b  = (const float*)d_in[7];
    const float* bih_b  = (const float*)d_in[8];
    const float* bhh_b  = (const float*)d_in[9];
    const float* W_fc   = (const float*)d_in[10];
    const float* b_fc   = (const float*)d_in[11];
    float* out   = (float*)d_out;
    float* hsnap = (float*)d_ws;   // 2*C*B*H*4 = 4 MiB of scratch

    gru_chain_kernel<<<64, 512, 0, stream>>>(x, h_prev, Wih_f, Whh_f, bih_f, bhh_f,
                                             Wih_b, Whh_b, bih_b, bhh_b, hsnap);
    fc_softmax_kernel<<<CC * BB, 64, 0, stream>>>(hsnap, W_fc, b_fc, out);
}

// Round 10
// 8614.740 us; speedup vs baseline: 1.6311x; 1.0145x over previous
//
#include <hip/hip_runtime.h>
#include <hip/hip_bf16.h>

#define BB 32
#define SS 128
#define CC 128
#define HH 128
#define OO 64

typedef _Float16 f16;
typedef f16 h2 __attribute__((ext_vector_type(2)));
typedef unsigned u32x4 __attribute__((ext_vector_type(4)));   // 4 packed f16x2 pairs

__device__ __forceinline__ float sigmoidf_(float x) {
    return 1.0f / (1.0f + __expf(-x));
}
__device__ __forceinline__ float tanh_fast_(float x) {
    return 1.0f - 2.0f / (__expf(2.0f * x) + 1.0f);  // |x| small here, no overflow
}

// Quad butterfly add on the VALU pipe. 0xB1 = xor1, 0x4E = xor2 (quad_perm).
template <int CTRL>
__device__ __forceinline__ float dpp_add(float v) {
    int m = __builtin_amdgcn_update_dpp(0, __builtin_bit_cast(int, v),
                                        CTRL, 0xF, 0xF, true);
    return v + __builtin_bit_cast(float, m);
}

__device__ __forceinline__ h2 as_h2(unsigned u) { return __builtin_bit_cast(h2, u); }

__device__ __forceinline__ unsigned pack2f(float a, float b) {
    h2 v; v[0] = (f16)a; v[1] = (f16)b;
    return __builtin_bit_cast(unsigned, v);
}
__device__ __forceinline__ u32x4 packrow8(const float* p) {
    u32x4 r;
    r.x = pack2f(p[0], p[1]);
    r.y = pack2f(p[2], p[3]);
    r.z = pack2f(p[4], p[5]);
    r.w = pack2f(p[6], p[7]);
    return r;
}

// 8-elem f16 dot, f32 accumulate. Every operand is ALREADY a packed f16x2
// pair in one VGPR (u32x4 component); as_h2 is a free bit_cast. R5-R8 showed
// a constant ~150 extra VALU ops/step that survived the residency fix (R8:
// weights resident, time unchanged) -> operand-shape packs for
// v_dot2_f32_f16 from h8 shufflevector extracts, not remat. Packed-pair
// form generates zero of them.
__device__ __forceinline__ float dot4x2(u32x4 w, u32x4 h, float acc) {
    acc = __builtin_amdgcn_fdot2(as_h2(w.x), as_h2(h.x), acc, false);
    acc = __builtin_amdgcn_fdot2(as_h2(w.y), as_h2(h.y), acc, false);
    acc = __builtin_amdgcn_fdot2(as_h2(w.z), as_h2(h.z), acc, false);
    acc = __builtin_amdgcn_fdot2(as_h2(w.w), as_h2(h.w), acc, false);
    return acc;
}

// One workgroup per (direction, batch). 512 threads = 8 waves, 2 waves/SIMD
// (LDS inflated >80KB -> 1 block/CU -> 256-VGPR allocator budget; grid = 64
// blocks on 256 CUs so this costs nothing). Thread (j = t>>2, q = t&3):
// gate rows j (r), j+128 (z), j+256 (n), quarter q of the 128-wide dot.
// Weights: 12 named u32x4 = 48 VGPRs of packed f16 pairs, asm-pinned (ext-
// vector type: uint4 struct form hits "tied indirect register inputs").
// h in LDS as f16, quarter q at half-offset q*40 (80B): the 4 b128 broadcast
// addresses land on disjoint bank quads. 2 DPP quad adds. 1 barrier/step.
__global__
__attribute__((amdgpu_flat_work_group_size(512, 512), amdgpu_waves_per_eu(2, 2)))
void gru_chain_kernel(
    const float* __restrict__ x,       // (B,S,C)
    const float* __restrict__ h_prev,  // (2,B,H)
    const float* __restrict__ Wih_f, const float* __restrict__ Whh_f,
    const float* __restrict__ bih_f, const float* __restrict__ bhh_f,
    const float* __restrict__ Wih_b, const float* __restrict__ Whh_b,
    const float* __restrict__ bih_b, const float* __restrict__ bhh_b,
    float* __restrict__ hsnap)         // (2, C, B, H) column-end snapshots
{
    const int wg = blockIdx.x;
    const int d  = wg >> 5;        // 0 = forward, 1 = backward
    const int b  = wg & 31;
    const int t  = threadIdx.x;    // 0..511
    const int j  = t >> 2;         // hidden index 0..127
    const int q  = t & 3;          // quarter of the dot

    const float* __restrict__ Wih = d ? Wih_b : Wih_f;
    const float* __restrict__ Whh = d ? Whh_b : Whh_f;
    const float* __restrict__ bih = d ? bih_b : bih_f;
    const float* __restrict__ bhh = d ? bhh_b : bhh_f;

    // xs padded: total LDS > 80KB -> 1 block/CU -> 256-VGPR budget.
    __shared__ float xs[SS * CC + 4608];
    __shared__ __align__(16) f16 hbuf[2][160];       // quarter q at half-offset q*40

    // stage x[b] (16384 contiguous floats) into LDS, coalesced float4
    {
        const float4* xb4 = reinterpret_cast<const float4*>(x + (size_t)b * SS * CC);
        float4* xs4 = reinterpret_cast<float4*>(xs);
        #pragma unroll
        for (int i = 0; i < 8; ++i) xs4[t + i * 512] = xb4[t + i * 512];
    }

    // 12 NAMED u32x4 (48 VGPRs) of packed f16 pairs: rows j, j+128, j+256, quarter q
    const float* rowr = Whh + (j          ) * HH + q * 32;
    const float* rowz = Whh + (j +     HH ) * HH + q * 32;
    const float* rown = Whh + (j + 2 * HH ) * HH + q * 32;
    u32x4 wrA = packrow8(rowr +  0), wrB = packrow8(rowr +  8),
          wrC = packrow8(rowr + 16), wrD = packrow8(rowr + 24);
    u32x4 wzA = packrow8(rowz +  0), wzB = packrow8(rowz +  8),
          wzC = packrow8(rowz + 16), wzD = packrow8(rowz + 24);
    u32x4 wnA = packrow8(rown +  0), wnB = packrow8(rown +  8),
          wnC = packrow8(rown + 16), wnD = packrow8(rown + 24);
    // pin: opaque to the rematerializer; 256-reg budget -> no spill pressure
    asm volatile("" : "+v"(wrA), "+v"(wrB), "+v"(wrC), "+v"(wrD),
                      "+v"(wzA), "+v"(wzB), "+v"(wzC), "+v"(wzD),
                      "+v"(wnA), "+v"(wnB), "+v"(wnC), "+v"(wnD));

    const float wih_r = Wih[j];
    const float wih_z = Wih[j + HH];
    const float wih_n = Wih[j + 2 * HH];
    const float brz_r4 = 0.25f * (bih[j]      + bhh[j]);       // quad-seeded bias
    const float brz_z4 = 0.25f * (bih[j + HH] + bhh[j + HH]);
    const float bhh_n4 = 0.25f * bhh[j + 2 * HH];
    const float bih_n  = bih[j + 2 * HH];

    float hp = h_prev[(d * BB + b) * HH + j];        // f32 carry (all 4 lanes)
    const int hwr = ((j >> 5) * 40) + (j & 31);      // skewed write slot (halves)
    if (q == 0) hbuf[0][hwr] = (f16)hp;
    __syncthreads();

    // One GRU step: read h (f16 pairs) from hbuf[SRC], write new h to hbuf[DST].
#define GSTEP(SRC, DST, TSS)                                                  \
    {                                                                         \
        const int tt = d ? (SS - 1 - (TSS)) : (TSS);                          \
        const float xv = xs[tt * CC + c];       /* uniform broadcast read */  \
        const u32x4* hb = reinterpret_cast<const u32x4*>(&hbuf[SRC][q * 40]); \
        const u32x4 hv0 = hb[0], hv1 = hb[1], hv2 = hb[2], hv3 = hb[3];       \
        float ra = dot4x2(wrA, hv0, brz_r4), rb = dot4x2(wrC, hv2, 0.0f);     \
        float za = dot4x2(wzA, hv0, brz_z4), zb = dot4x2(wzC, hv2, 0.0f);     \
        float na = dot4x2(wnA, hv0, bhh_n4), nb = dot4x2(wnC, hv2, 0.0f);     \
        ra = dot4x2(wrB, hv1, ra);  rb = dot4x2(wrD, hv3, rb);                \
        za = dot4x2(wzB, hv1, za);  zb = dot4x2(wzD, hv3, zb);                \
        na = dot4x2(wnB, hv1, na);  nb = dot4x2(wnD, hv3, nb);                \
        float sr = ra + rb, sz = za + zb, sn = na + nb;                       \
        sr = dpp_add<0xB1>(sr); sr = dpp_add<0x4E>(sr);                       \
        sz = dpp_add<0xB1>(sz); sz = dpp_add<0x4E>(sz);                       \
        sn = dpp_add<0xB1>(sn); sn = dpp_add<0x4E>(sn);                       \
        const float r = sigmoidf_(fmaf(xv, wih_r, sr));                       \
        const float z = sigmoidf_(fmaf(xv, wih_z, sz));                       \
        const float gi_n = fmaf(xv, wih_n, bih_n);                            \
        const float n = tanh_fast_(fmaf(r, sn, gi_n));                        \
        hp = fmaf(z, hp - n, n);                /* (1-z)*n + z*h  (f32) */    \
        if (q == 0) hbuf[DST][hwr] = (f16)hp;                                 \
        __syncthreads();                                                      \
    }

    for (int c = 0; c < CC; ++c) {
        for (int ts = 0; ts < SS; ts += 2) {
            GSTEP(0, 1, ts)        // h: buf0 -> buf1
            GSTEP(1, 0, ts + 1)    // h: buf1 -> buf0
        }
        if (q == 0) {
            hsnap[(((size_t)d * CC + c) * BB + b) * HH + j] = hp;
        }
    }
#undef GSTEP
}

// One block (= one wave of 64 threads) per (c,b): FC + ReLU + softmax over O=64.
__global__ __launch_bounds__(64) void fc_softmax_kernel(
    const float* __restrict__ hsnap,   // (2, C, B, H)
    const float* __restrict__ W_fc,    // (O, 2H)
    const float* __restrict__ b_fc,    // (O,)
    float* __restrict__ out)           // (B, C, O)
{
    const int cb = blockIdx.x;         // c * B + b
    const int c  = cb >> 5;
    const int b  = cb & 31;
    const int o  = threadIdx.x;        // 0..63

    __shared__ float feat[2 * HH];     // [hf, hb]
    #pragma unroll
    for (int i = 0; i < 4; ++i) {
        const int idx = i * 64 + o;            // 0..255
        const int dd  = idx >> 7;              // 0: hf, 1: hb
        const int jj  = idx & (HH - 1);
        feat[idx] = hsnap[(((size_t)dd * CC + c) * BB + b) * HH + jj];
    }
    __syncthreads();

    float acc = 0.f;
    const float4* wrow = reinterpret_cast<const float4*>(W_fc + o * 2 * HH);
    const float4* f4   = reinterpret_cast<const float4*>(feat);
    #pragma unroll
    for (int k = 0; k < 64; ++k) {
        const float4 wv = wrow[k];
        const float4 fv = f4[k];
        acc = fmaf(wv.x, fv.x, acc);
        acc = fmaf(wv.y, fv.y, acc);
        acc = fmaf(wv.z, fv.z, acc);
        acc = fmaf(wv.w, fv.w, acc);
    }
    float v = fmaxf(acc + b_fc[o], 0.0f);

    float m = v;
    #pragma unroll
    for (int off = 32; off; off >>= 1) m = fmaxf(m, __shfl_xor(m, off));
    const float e = __expf(v - m);
    float ssum = e;
    #pragma unroll
    for (int off = 32; off; off >>= 1) ssum += __shfl_xor(ssum, off);

    out[((size_t)b * CC + c) * OO + o] = e / ssum;
}

extern "C" void kernel_launch(void* const* d_in, const int* in_sizes, int n_in,
                              void* d_out, int out_size, void* d_ws, size_t ws_size,
                              hipStream_t stream) {
    const float* x      = (const float*)d_in[0];
    const float* h_prev = (const float*)d_in[1];
    const float* Wih_f  = (const float*)d_in[2];
    const float* Whh_f  = (const float*)d_in[3];
    const float* bih_f  = (const float*)d_in[4];
    const float* bhh_f  = (const float*)d_in[5];
    const float* Wih_b  = (const float*)d_in[6];
    const float* Whh_b  = (const float*)d_in[7];
    const float* bih_b  = (const float*)d_in[8];
    const float* bhh_b  = (const float*)d_in[9];
    const float* W_fc   = (const float*)d_in[10];
    const float* b_fc   = (const float*)d_in[11];
    float* out   = (float*)d_out;
    float* hsnap = (float*)d_ws;   // 2*C*B*H*4 = 4 MiB of scratch

    gru_chain_kernel<<<64, 512, 0, stream>>>(x, h_prev, Wih_f, Whh_f, bih_f, bhh_f,
                                             Wih_b, Whh_b, bih_b, bhh_b, hsnap);
    fc_softmax_kernel<<<CC * BB, 64, 0, stream>>>(hsnap, W_fc, b_fc, out);
}